// Round 2
// baseline (452.825 us; speedup 1.0000x reference)
//
#include <hip/hip_runtime.h>

#define NMOV 100000
#define NUSR 50000
#define NN   150000
#define DIM  128
#define HID  256
#define NE   500000

#define MBLK 128           // rows per block
#define LDK  264           // LDS row stride in shorts for the A/h tile
#define HWS  136           // LDS row stride (shorts) for hW epilogue staging (16B-aligned rows)
#define NB_SCAN ((NN + 255) / 256)   // 586

typedef __attribute__((ext_vector_type(8))) short bf16x8;
typedef __attribute__((ext_vector_type(4))) float f32x4;

__device__ __forceinline__ short f2bf(float f) {
  union { float f; unsigned u; } v; v.f = f;
  unsigned r = (v.u + 0x7fffu + ((v.u >> 16) & 1u)) >> 16;   // RNE
  return (short)r;
}
__device__ __forceinline__ float bf2f(short s) {
  union { unsigned u; float f; } v;
  v.u = ((unsigned)(unsigned short)s) << 16;
  return v.f;
}

// ================= CSR build =================
__global__ __launch_bounds__(256) void deg_kernel(const int* __restrict__ dst,
                                                  int* __restrict__ degi) {
  int e = blockIdx.x * 256 + threadIdx.x;
  if (e < NE) atomicAdd(&degi[dst[e]], 1);
}

__global__ __launch_bounds__(256) void scan1_kernel(const int* __restrict__ degi,
                                                    int* __restrict__ pre,
                                                    int* __restrict__ bsum) {
  __shared__ int s[256];
  int tid = threadIdx.x;
  int i = blockIdx.x * 256 + tid;
  int v = (i < NN) ? degi[i] : 0;
  s[tid] = v;
  __syncthreads();
#pragma unroll
  for (int off = 1; off < 256; off <<= 1) {
    int t = (tid >= off) ? s[tid - off] : 0;
    __syncthreads();
    s[tid] += t;
    __syncthreads();
  }
  if (i < NN) pre[i] = s[tid] - v;
  if (tid == 255) bsum[blockIdx.x] = s[255];
}

__global__ __launch_bounds__(1024) void scan2_kernel(int* __restrict__ bsum) {
  __shared__ int s[1024];
  int tid = threadIdx.x;
  int v = (tid < NB_SCAN) ? bsum[tid] : 0;
  s[tid] = v;
  __syncthreads();
#pragma unroll
  for (int off = 1; off < 1024; off <<= 1) {
    int t = (tid >= off) ? s[tid - off] : 0;
    __syncthreads();
    s[tid] += t;
    __syncthreads();
  }
  bsum[tid] = s[tid] - v;   // exclusive
}

__global__ __launch_bounds__(256) void scan3_kernel(const int* __restrict__ pre,
                                                    const int* __restrict__ bsum,
                                                    int* __restrict__ rowptr) {
  int i = blockIdx.x * 256 + threadIdx.x;
  if (i < NN) rowptr[i] = pre[i] + bsum[blockIdx.x];
  if (i == 0) rowptr[NN] = NE;
}

// stores ORIGINAL EDGE ID per CSR slot (src recovered via src[eid] — 4B L2 load)
__global__ __launch_bounds__(256) void csr_scatter_kernel(const int* __restrict__ dst,
                                                          const int* __restrict__ rowptr,
                                                          int* __restrict__ cnt,
                                                          int* __restrict__ eidx) {
  int e = blockIdx.x * 256 + threadIdx.x;
  if (e >= NE) return;
  int d = dst[e];
  int pos = rowptr[d] + atomicAdd(&cnt[d], 1);
  eidx[pos] = e;
}

// ================= bf16 conversion of node features =================
__global__ __launch_bounds__(256) void convx_kernel(const float* __restrict__ movie,
                                                    const float* __restrict__ user,
                                                    short* __restrict__ xb) {
  int c = blockIdx.x * 256 + threadIdx.x;        // chunk of 8
  if (c >= NN * DIM / 8) return;
  size_t base = (size_t)c * 8;
  const float* srcp = (base < (size_t)NMOV * DIM) ? (movie + base)
                                                  : (user + (base - (size_t)NMOV * DIM));
  float4 v0 = ((const float4*)srcp)[0];
  float4 v1 = ((const float4*)srcp)[1];
  short4 s0 = make_short4(f2bf(v0.x), f2bf(v0.y), f2bf(v0.z), f2bf(v0.w));
  short4 s1 = make_short4(f2bf(v1.x), f2bf(v1.y), f2bf(v1.z), f2bf(v1.w));
  *(short4*)(xb + base)     = s0;
  *(short4*)(xb + base + 4) = s1;
}

// ================= weight swizzle: bf16, MFMA-fragment-linear =================
__global__ __launch_bounds__(256) void convw_kernel(const float* __restrict__ Wl1,
                                                    const float* __restrict__ Wr1,
                                                    const float* __restrict__ Wl2,
                                                    const float* __restrict__ Wr2,
                                                    short* __restrict__ Wf1,
                                                    short* __restrict__ Wf2) {
  int t = blockIdx.x * 256 + threadIdx.x;   // 2*16*8*64 = 16384 threads
  int stage = t >> 13;
  int r = t & 8191;
  int n    = r >> 9;
  int kk   = (r >> 6) & 7;
  int lane = r & 63;
  int ncol  = n * 16 + (lane & 15);
  int kbase = kk * 32 + (lane >> 4) * 8;
  short vals[8];
#pragma unroll
  for (int jj = 0; jj < 8; jj++) {
    int k = kbase + jj;
    float v;
    if (stage == 0)
      v = (k < 128) ? Wl1[(size_t)k * HID + ncol] : Wr1[(size_t)(k - 128) * HID + ncol];
    else
      v = (ncol < 128) ? Wl2[(size_t)k * DIM + ncol] : Wr2[(size_t)k * DIM + (ncol - 128)];
    vals[jj] = f2bf(v);
  }
  short* outp = (stage == 0 ? Wf1 : Wf2) + ((size_t)(n * 8 + kk) << 9) + lane * 8;
  *(short4*)(outp)     = make_short4(vals[0], vals[1], vals[2], vals[3]);
  *(short4*)(outp + 4) = make_short4(vals[4], vals[5], vals[6], vals[7]);
}

// ================= gather1: aggb[node] = bf16(mean of xb[src rows]) =================
__global__ __launch_bounds__(256) void gather1_kernel(const int* __restrict__ rowptr,
                                                      const int* __restrict__ eidx,
                                                      const int* __restrict__ src,
                                                      const short* __restrict__ xb,
                                                      short* __restrict__ aggb) {
  int t = blockIdx.x * 256 + threadIdx.x;
  int node = t >> 4, l = t & 15;
  if (node >= NN) return;
  int b = rowptr[node], e = rowptr[node + 1];
  float acc[8] = {0.f, 0.f, 0.f, 0.f, 0.f, 0.f, 0.f, 0.f};
  int j = b;
  for (; j + 1 < e; j += 2) {
    int e0 = eidx[j], e1 = eidx[j + 1];
    int s0 = src[e0], s1 = src[e1];
    const short* r0 = xb + (size_t)s0 * DIM;
    const short* r1 = xb + (size_t)s1 * DIM;
    short4 p0 = *(const short4*)(r0 + l * 4);
    short4 q0 = *(const short4*)(r0 + 64 + l * 4);
    short4 p1 = *(const short4*)(r1 + l * 4);
    short4 q1 = *(const short4*)(r1 + 64 + l * 4);
    acc[0] += bf2f(p0.x) + bf2f(p1.x); acc[1] += bf2f(p0.y) + bf2f(p1.y);
    acc[2] += bf2f(p0.z) + bf2f(p1.z); acc[3] += bf2f(p0.w) + bf2f(p1.w);
    acc[4] += bf2f(q0.x) + bf2f(q1.x); acc[5] += bf2f(q0.y) + bf2f(q1.y);
    acc[6] += bf2f(q0.z) + bf2f(q1.z); acc[7] += bf2f(q0.w) + bf2f(q1.w);
  }
  if (j < e) {
    int s0 = src[eidx[j]];
    const short* r0 = xb + (size_t)s0 * DIM;
    short4 p0 = *(const short4*)(r0 + l * 4);
    short4 q0 = *(const short4*)(r0 + 64 + l * 4);
    acc[0] += bf2f(p0.x); acc[1] += bf2f(p0.y); acc[2] += bf2f(p0.z); acc[3] += bf2f(p0.w);
    acc[4] += bf2f(q0.x); acc[5] += bf2f(q0.y); acc[6] += bf2f(q0.z); acc[7] += bf2f(q0.w);
  }
  float inv = 1.0f / fmaxf((float)(e - b), 1.0f);
  short4 o0 = make_short4(f2bf(acc[0] * inv), f2bf(acc[1] * inv),
                          f2bf(acc[2] * inv), f2bf(acc[3] * inv));
  short4 o1 = make_short4(f2bf(acc[4] * inv), f2bf(acc[5] * inv),
                          f2bf(acc[6] * inv), f2bf(acc[7] * inv));
  *(short4*)(aggb + (size_t)node * DIM + l * 4)      = o0;
  *(short4*)(aggb + (size_t)node * DIM + 64 + l * 4) = o1;
}

// ================= fused MFMA: both GEMMs, h stays in LDS =================
// 512 threads = 8 thin waves; each wave owns 32 rows x 128 cols.
// Per-wave regs: af[2][8]=64 + bw[8]=32 + acc=8 -> fits 128-VGPR budget for
// __launch_bounds__(512,4): 2 blocks/CU x 8 waves = 16 waves/CU (4/SIMD).
// Occupancy (TLP) replaces the removed bn-prefetch for L2 latency hiding.
__global__ __launch_bounds__(512, 4) void fused_mfma_kernel(
    const short* __restrict__ xb, short* ab_hw,
    const short* __restrict__ Wf1, const float* __restrict__ bl1,
    const short* __restrict__ Wf2, const float* __restrict__ bl2,
    float* __restrict__ dref) {
  __shared__ __align__(16) short tile[MBLK][LDK];   // 67.6 KB -> 2 blocks/CU
  const int tid = threadIdx.x;
  const int row0 = blockIdx.x * MBLK;

  // stage A_cat = [aggb | xb] bf16, 16B chunks
  for (int idx = tid; idx < MBLK * 32; idx += 512) {
    int r   = idx >> 5;
    int c16 = idx & 31;
    int row = row0 + r;
    int col = c16 * 8;
    int4 v = make_int4(0, 0, 0, 0);
    if (row < NN) {
      const short* srcp = (col < DIM) ? (ab_hw + (size_t)row * DIM + col)
                                      : (xb + (size_t)row * DIM + (col - DIM));
      v = *(const int4*)srcp;
    }
    *(int4*)&tile[r][col] = v;
  }
  __syncthreads();

  const int lane = tid & 63;
  const int wv   = tid >> 6;          // 0..7
  const int c    = lane & 15;
  const int quad = lane >> 4;
  const int wrow = (wv & 3) * 32;     // row quarter (32 rows = 2 groups of 16)
  const int ch   = wv >> 2;           // col half

  // ---- stage 1: h = relu(A_cat @ W1 + bl1) -> LDS ----
  {
    bf16x8 af[2][8];
#pragma unroll
    for (int rg = 0; rg < 2; rg++)
#pragma unroll
      for (int kk = 0; kk < 8; kk++)
        af[rg][kk] = *(const bf16x8*)&tile[wrow + rg * 16 + c][kk * 32 + quad * 8];
    __syncthreads();                  // A in regs everywhere -> safe to overwrite tile

#pragma unroll 1
    for (int nn = 0; nn < 8; nn++) {
      int n = ch * 8 + nn;
      const short* wq = Wf1 + ((size_t)(n * 8) << 9) + lane * 8;
      bf16x8 bw[8];
#pragma unroll
      for (int kk = 0; kk < 8; kk++)
        bw[kk] = *(const bf16x8*)(wq + ((size_t)kk << 9));
      f32x4 a0 = {0.f, 0.f, 0.f, 0.f}, a1 = {0.f, 0.f, 0.f, 0.f};
#pragma unroll
      for (int kk = 0; kk < 8; kk++) {
        a0 = __builtin_amdgcn_mfma_f32_16x16x32_bf16(af[0][kk], bw[kk], a0, 0, 0, 0);
        a1 = __builtin_amdgcn_mfma_f32_16x16x32_bf16(af[1][kk], bw[kk], a1, 0, 0, 0);
      }
      float bv = bl1[n * 16 + c];
#pragma unroll
      for (int i = 0; i < 4; i++) {
        tile[wrow +      quad * 4 + i][n * 16 + c] = f2bf(fmaxf(a0[i] + bv, 0.0f));
        tile[wrow + 16 + quad * 4 + i][n * 16 + c] = f2bf(fmaxf(a1[i] + bv, 0.0f));
      }
    }
  }
  __syncthreads();

  // ---- stage 2: hW (cols 0..127, ch=0) via LDS; dref (cols 128..255, ch=1) direct ----
  {
    bf16x8 af[2][8];
#pragma unroll
    for (int rg = 0; rg < 2; rg++)
#pragma unroll
      for (int kk = 0; kk < 8; kk++)
        af[rg][kk] = *(const bf16x8*)&tile[wrow + rg * 16 + c][kk * 32 + quad * 8];
    __syncthreads();                   // all waves done reading h -> safe to reuse tile

    short* hw_s = &tile[0][0];         // [128][HWS] bf16 staging for hW half

#pragma unroll 1
    for (int nn = 0; nn < 8; nn++) {
      int n = ch * 8 + nn;
      const short* wq = Wf2 + ((size_t)(n * 8) << 9) + lane * 8;
      bf16x8 bw[8];
#pragma unroll
      for (int kk = 0; kk < 8; kk++)
        bw[kk] = *(const bf16x8*)(wq + ((size_t)kk << 9));
      f32x4 a0 = {0.f, 0.f, 0.f, 0.f}, a1 = {0.f, 0.f, 0.f, 0.f};
#pragma unroll
      for (int kk = 0; kk < 8; kk++) {
        a0 = __builtin_amdgcn_mfma_f32_16x16x32_bf16(af[0][kk], bw[kk], a0, 0, 0, 0);
        a1 = __builtin_amdgcn_mfma_f32_16x16x32_bf16(af[1][kk], bw[kk], a1, 0, 0, 0);
      }
      int col = n * 16 + c;
      if (ch == 0) {                   // wave-uniform branch
#pragma unroll
        for (int i = 0; i < 4; i++) {
          hw_s[(wrow +      quad * 4 + i) * HWS + col] = f2bf(a0[i]);
          hw_s[(wrow + 16 + quad * 4 + i) * HWS + col] = f2bf(a1[i]);
        }
      } else {
        float bv = bl2[col - 128];
#pragma unroll
        for (int i = 0; i < 4; i++) {
          int r0 = row0 + wrow + quad * 4 + i;
          if (r0 < NN)      dref[(size_t)r0 * DIM + (col - 128)]        = a0[i] + bv;
          if (r0 + 16 < NN) dref[(size_t)(r0 + 16) * DIM + (col - 128)] = a1[i] + bv;
        }
      }
    }
  }
  __syncthreads();

  // stream hW out coalesced (full 256B bf16 rows = 16 int4 chunks per row)
  {
    short* hw_s = &tile[0][0];
    for (int idx = tid; idx < MBLK * 16; idx += 512) {
      int r  = idx >> 4;
      int c8 = idx & 15;
      int row = row0 + r;
      if (row < NN) {
        int4 v = *(const int4*)&hw_s[r * HWS + c8 * 8];
        *(int4*)(ab_hw + (size_t)row * DIM + c8 * 8) = v;
      }
    }
  }
}

// ================= gather2: dref[node] += mean(hWb[src]); drefb = bf16(dref) ==========
__global__ __launch_bounds__(256) void gather2_kernel(const int* __restrict__ rowptr,
                                                      const int* __restrict__ eidx,
                                                      const int* __restrict__ src,
                                                      const short* __restrict__ hWb,
                                                      float* __restrict__ dref,
                                                      short* __restrict__ drefb) {
  int t = blockIdx.x * 256 + threadIdx.x;
  int node = t >> 4, l = t & 15;
  if (node >= NN) return;
  int b = rowptr[node], e = rowptr[node + 1];
  // hoist the dref RMW loads: independent of the gather chain -> overlaps latency
  float* dr = dref + (size_t)node * DIM;
  float4 c0 = *(float4*)(dr + l * 4);
  float4 c1 = *(float4*)(dr + 64 + l * 4);
  float acc[8] = {0.f, 0.f, 0.f, 0.f, 0.f, 0.f, 0.f, 0.f};
  int j = b;
  for (; j + 1 < e; j += 2) {
    int e0 = eidx[j], e1 = eidx[j + 1];
    int s0 = src[e0], s1 = src[e1];
    const short* r0 = hWb + (size_t)s0 * DIM;
    const short* r1 = hWb + (size_t)s1 * DIM;
    short4 p0 = *(const short4*)(r0 + l * 4);
    short4 q0 = *(const short4*)(r0 + 64 + l * 4);
    short4 p1 = *(const short4*)(r1 + l * 4);
    short4 q1 = *(const short4*)(r1 + 64 + l * 4);
    acc[0] += bf2f(p0.x) + bf2f(p1.x); acc[1] += bf2f(p0.y) + bf2f(p1.y);
    acc[2] += bf2f(p0.z) + bf2f(p1.z); acc[3] += bf2f(p0.w) + bf2f(p1.w);
    acc[4] += bf2f(q0.x) + bf2f(q1.x); acc[5] += bf2f(q0.y) + bf2f(q1.y);
    acc[6] += bf2f(q0.z) + bf2f(q1.z); acc[7] += bf2f(q0.w) + bf2f(q1.w);
  }
  if (j < e) {
    int s0 = src[eidx[j]];
    const short* r0 = hWb + (size_t)s0 * DIM;
    short4 p0 = *(const short4*)(r0 + l * 4);
    short4 q0 = *(const short4*)(r0 + 64 + l * 4);
    acc[0] += bf2f(p0.x); acc[1] += bf2f(p0.y); acc[2] += bf2f(p0.z); acc[3] += bf2f(p0.w);
    acc[4] += bf2f(q0.x); acc[5] += bf2f(q0.y); acc[6] += bf2f(q0.z); acc[7] += bf2f(q0.w);
  }
  float inv = 1.0f / fmaxf((float)(e - b), 1.0f);
  c0.x += acc[0] * inv; c0.y += acc[1] * inv; c0.z += acc[2] * inv; c0.w += acc[3] * inv;
  c1.x += acc[4] * inv; c1.y += acc[5] * inv; c1.z += acc[6] * inv; c1.w += acc[7] * inv;
  *(float4*)(dr + l * 4)      = c0;
  *(float4*)(dr + 64 + l * 4) = c1;
  short4 o0 = make_short4(f2bf(c0.x), f2bf(c0.y), f2bf(c0.z), f2bf(c0.w));
  short4 o1 = make_short4(f2bf(c1.x), f2bf(c1.y), f2bf(c1.z), f2bf(c1.w));
  *(short4*)(drefb + (size_t)node * DIM + l * 4)      = o0;
  *(short4*)(drefb + (size_t)node * DIM + 64 + l * 4) = o1;
}

// ================= edge scoring, CSR-ordered: dst row cached in regs ==========
__global__ __launch_bounds__(256) void score_kernel(const int* __restrict__ rowptr,
                                                    const int* __restrict__ eidx,
                                                    const int* __restrict__ src,
                                                    const short* __restrict__ drefb,
                                                    float* __restrict__ out) {
  int t = blockIdx.x * 256 + threadIdx.x;
  int node = t >> 4, l = t & 15;
  if (node >= NN) return;
  int b = rowptr[node], e = rowptr[node + 1];
  if (b == e) return;
  const short* rd = drefb + (size_t)node * DIM;
  short4 d0 = *(const short4*)(rd + l * 4);
  short4 d1 = *(const short4*)(rd + 64 + l * 4);
  float f0 = bf2f(d0.x), f1 = bf2f(d0.y), f2 = bf2f(d0.z), f3 = bf2f(d0.w);
  float f4 = bf2f(d1.x), f5 = bf2f(d1.y), f6 = bf2f(d1.z), f7 = bf2f(d1.w);
  int j = b;
  for (; j + 1 < e; j += 2) {
    int e0 = eidx[j], e1 = eidx[j + 1];
    int s0 = src[e0], s1 = src[e1];
    const short* ra = drefb + (size_t)s0 * DIM;
    const short* rb = drefb + (size_t)s1 * DIM;
    short4 a0 = *(const short4*)(ra + l * 4);
    short4 a1 = *(const short4*)(ra + 64 + l * 4);
    short4 b0 = *(const short4*)(rb + l * 4);
    short4 b1 = *(const short4*)(rb + 64 + l * 4);
    float sA = bf2f(a0.x) * f0 + bf2f(a0.y) * f1 + bf2f(a0.z) * f2 + bf2f(a0.w) * f3 +
               bf2f(a1.x) * f4 + bf2f(a1.y) * f5 + bf2f(a1.z) * f6 + bf2f(a1.w) * f7;
    float sB = bf2f(b0.x) * f0 + bf2f(b0.y) * f1 + bf2f(b0.z) * f2 + bf2f(b0.w) * f3 +
               bf2f(b1.x) * f4 + bf2f(b1.y) * f5 + bf2f(b1.z) * f6 + bf2f(b1.w) * f7;
#pragma unroll
    for (int off = 1; off < 16; off <<= 1) {
      sA += __shfl_xor(sA, off, 16);
      sB += __shfl_xor(sB, off, 16);
    }
    if (l == 0) { out[e0] = sA; out[e1] = sB; }
  }
  if (j < e) {
    int e0 = eidx[j];
    int s0 = src[e0];
    const short* ra = drefb + (size_t)s0 * DIM;
    short4 a0 = *(const short4*)(ra + l * 4);
    short4 a1 = *(const short4*)(ra + 64 + l * 4);
    float sA = bf2f(a0.x) * f0 + bf2f(a0.y) * f1 + bf2f(a0.z) * f2 + bf2f(a0.w) * f3 +
               bf2f(a1.x) * f4 + bf2f(a1.y) * f5 + bf2f(a1.z) * f6 + bf2f(a1.w) * f7;
#pragma unroll
    for (int off = 1; off < 16; off <<= 1) sA += __shfl_xor(sA, off, 16);
    if (l == 0) out[e0] = sA;
  }
}

extern "C" void kernel_launch(void* const* d_in, const int* in_sizes, int n_in,
                              void* d_out, int out_size, void* d_ws, size_t ws_size,
                              hipStream_t stream) {
  const int* ei    = (const int*)d_in[0];
  const int* src   = ei;
  const int* dst   = ei + NE;
  // d_in[1] = edge_attr (unused by the reference)
  const float* movie = (const float*)d_in[2];
  const float* user  = (const float*)d_in[3];
  const float* Wl1   = (const float*)d_in[4];
  const float* bl1   = (const float*)d_in[5];
  const float* Wr1   = (const float*)d_in[6];
  const float* Wl2   = (const float*)d_in[7];
  const float* bl2   = (const float*)d_in[8];
  const float* Wr2   = (const float*)d_in[9];

  float* out  = (float*)d_out;       // [NE] ratings
  float* dref = out + NE;            // [NN*DIM] refined (f32 output)

  // workspace (~81.6 MB): ints | xb(+drefb alias) | aggb(+hWb alias) | Wf1 | Wf2
  int* degi   = (int*)d_ws;                    // [NN] (zeroed)
  int* cnt    = degi + NN;                     // [NN] (zeroed)
  int* pre    = cnt + NN;                      // [NN]
  int* bsum   = pre + NN;                      // [1024]
  int* rowptr = bsum + 1024;                   // [NN+1]
  int* eidx   = rowptr + NN + 1;               // [NE] original edge id per CSR slot
  short* xb   = (short*)(((uintptr_t)(eidx + NE) + 15) & ~(uintptr_t)15);  // [NN*DIM] bf16
  short* aggb = xb + (size_t)NN * DIM;         // [NN*DIM] bf16 (later reused as hWb)
  short* Wf1  = aggb + (size_t)NN * DIM;       // [65536]
  short* Wf2  = Wf1 + 65536;                   // [65536]
  short* hWb   = aggb;                         // alias: fused overwrites its own rows
  short* drefb = xb;                           // alias: xb dead after fused

  hipMemsetAsync(degi, 0, (size_t)2 * NN * sizeof(int), stream);

  deg_kernel<<<(NE + 255) / 256, 256, 0, stream>>>(dst, degi);
  scan1_kernel<<<NB_SCAN, 256, 0, stream>>>(degi, pre, bsum);
  scan2_kernel<<<1, 1024, 0, stream>>>(bsum);
  scan3_kernel<<<NB_SCAN, 256, 0, stream>>>(pre, bsum, rowptr);
  csr_scatter_kernel<<<(NE + 255) / 256, 256, 0, stream>>>(dst, rowptr, cnt, eidx);
  convx_kernel<<<NN * DIM / 8 / 256, 256, 0, stream>>>(movie, user, xb);
  convw_kernel<<<16384 / 256, 256, 0, stream>>>(Wl1, Wr1, Wl2, Wr2, Wf1, Wf2);
  gather1_kernel<<<NN * 16 / 256, 256, 0, stream>>>(rowptr, eidx, src, xb, aggb);
  fused_mfma_kernel<<<(NN + MBLK - 1) / MBLK, 512, 0, stream>>>(
      xb, aggb, Wf1, bl1, Wf2, bl2, dref);
  gather2_kernel<<<NN * 16 / 256, 256, 0, stream>>>(rowptr, eidx, src, hWb, dref, drefb);
  score_kernel<<<NN * 16 / 256, 256, 0, stream>>>(rowptr, eidx, src, drefb, out);
}

// Round 3
// 404.608 us; speedup vs baseline: 1.1192x; 1.1192x over previous
//
#include <hip/hip_runtime.h>

#define NMOV 100000
#define NUSR 50000
#define NN   150000
#define DIM  128
#define HID  256
#define NE   500000

#define MBLK 128           // rows per block
#define LDK  264           // LDS row stride in shorts for the A/h tile
#define NB_SCAN ((NN + 255) / 256)   // 586

typedef __attribute__((ext_vector_type(8))) short bf16x8;
typedef __attribute__((ext_vector_type(4))) float f32x4;

__device__ __forceinline__ short f2bf(float f) {
  union { float f; unsigned u; } v; v.f = f;
  unsigned r = (v.u + 0x7fffu + ((v.u >> 16) & 1u)) >> 16;   // RNE
  return (short)r;
}
__device__ __forceinline__ float bf2f(short s) {
  union { unsigned u; float f; } v;
  v.u = ((unsigned)(unsigned short)s) << 16;
  return v.f;
}

// ================= CSR build =================
__global__ __launch_bounds__(256) void deg_kernel(const int* __restrict__ dst,
                                                  int* __restrict__ degi) {
  int e = blockIdx.x * 256 + threadIdx.x;
  if (e < NE) atomicAdd(&degi[dst[e]], 1);
}

__global__ __launch_bounds__(256) void scan1_kernel(const int* __restrict__ degi,
                                                    int* __restrict__ pre,
                                                    int* __restrict__ bsum) {
  __shared__ int s[256];
  int tid = threadIdx.x;
  int i = blockIdx.x * 256 + tid;
  int v = (i < NN) ? degi[i] : 0;
  s[tid] = v;
  __syncthreads();
#pragma unroll
  for (int off = 1; off < 256; off <<= 1) {
    int t = (tid >= off) ? s[tid - off] : 0;
    __syncthreads();
    s[tid] += t;
    __syncthreads();
  }
  if (i < NN) pre[i] = s[tid] - v;
  if (tid == 255) bsum[blockIdx.x] = s[255];
}

__global__ __launch_bounds__(1024) void scan2_kernel(int* __restrict__ bsum) {
  __shared__ int s[1024];
  int tid = threadIdx.x;
  int v = (tid < NB_SCAN) ? bsum[tid] : 0;
  s[tid] = v;
  __syncthreads();
#pragma unroll
  for (int off = 1; off < 1024; off <<= 1) {
    int t = (tid >= off) ? s[tid - off] : 0;
    __syncthreads();
    s[tid] += t;
    __syncthreads();
  }
  bsum[tid] = s[tid] - v;   // exclusive
}

__global__ __launch_bounds__(256) void scan3_kernel(const int* __restrict__ pre,
                                                    const int* __restrict__ bsum,
                                                    int* __restrict__ rowptr) {
  int i = blockIdx.x * 256 + threadIdx.x;
  if (i < NN) rowptr[i] = pre[i] + bsum[blockIdx.x];
  if (i == 0) rowptr[NN] = NE;
}

// stores SRC node id per CSR slot (single indirection in the gathers)
__global__ __launch_bounds__(256) void csr_scatter_kernel(const int* __restrict__ src,
                                                          const int* __restrict__ dst,
                                                          const int* __restrict__ rowptr,
                                                          int* __restrict__ cnt,
                                                          int* __restrict__ esrc) {
  int e = blockIdx.x * 256 + threadIdx.x;
  if (e >= NE) return;
  int d = dst[e];
  int pos = rowptr[d] + atomicAdd(&cnt[d], 1);
  esrc[pos] = src[e];
}

// ================= bf16 conversion of node features =================
__global__ __launch_bounds__(256) void convx_kernel(const float* __restrict__ movie,
                                                    const float* __restrict__ user,
                                                    short* __restrict__ xb) {
  int c = blockIdx.x * 256 + threadIdx.x;        // chunk of 8
  if (c >= NN * DIM / 8) return;
  size_t base = (size_t)c * 8;
  const float* srcp = (base < (size_t)NMOV * DIM) ? (movie + base)
                                                  : (user + (base - (size_t)NMOV * DIM));
  float4 v0 = ((const float4*)srcp)[0];
  float4 v1 = ((const float4*)srcp)[1];
  short4 s0 = make_short4(f2bf(v0.x), f2bf(v0.y), f2bf(v0.z), f2bf(v0.w));
  short4 s1 = make_short4(f2bf(v1.x), f2bf(v1.y), f2bf(v1.z), f2bf(v1.w));
  *(short4*)(xb + base)     = s0;
  *(short4*)(xb + base + 4) = s1;
}

// ================= weight swizzle: bf16, MFMA-fragment-linear =================
__global__ __launch_bounds__(256) void convw_kernel(const float* __restrict__ Wl1,
                                                    const float* __restrict__ Wr1,
                                                    const float* __restrict__ Wl2,
                                                    const float* __restrict__ Wr2,
                                                    short* __restrict__ Wf1,
                                                    short* __restrict__ Wf2) {
  int t = blockIdx.x * 256 + threadIdx.x;   // 2*16*8*64 = 16384 threads
  int stage = t >> 13;
  int r = t & 8191;
  int n    = r >> 9;
  int kk   = (r >> 6) & 7;
  int lane = r & 63;
  int ncol  = n * 16 + (lane & 15);
  int kbase = kk * 32 + (lane >> 4) * 8;
  short vals[8];
#pragma unroll
  for (int jj = 0; jj < 8; jj++) {
    int k = kbase + jj;
    float v;
    if (stage == 0)
      v = (k < 128) ? Wl1[(size_t)k * HID + ncol] : Wr1[(size_t)(k - 128) * HID + ncol];
    else
      v = (ncol < 128) ? Wl2[(size_t)k * DIM + ncol] : Wr2[(size_t)k * DIM + (ncol - 128)];
    vals[jj] = f2bf(v);
  }
  short* outp = (stage == 0 ? Wf1 : Wf2) + ((size_t)(n * 8 + kk) << 9) + lane * 8;
  *(short4*)(outp)     = make_short4(vals[0], vals[1], vals[2], vals[3]);
  *(short4*)(outp + 4) = make_short4(vals[4], vals[5], vals[6], vals[7]);
}

// ================= gather1: aggb[node] = bf16(mean of xb[src rows]) =================
// 16 lanes/node, one b128 per lane per row; clamped 4-batch (no serial tail).
__global__ __launch_bounds__(256) void gather1_kernel(const int* __restrict__ rowptr,
                                                      const int* __restrict__ esrc,
                                                      const short* __restrict__ xb,
                                                      short* __restrict__ aggb) {
  int t = blockIdx.x * 256 + threadIdx.x;
  int node = t >> 4, l = t & 15;
  if (node >= NN) return;
  int b = rowptr[node], e = rowptr[node + 1];
  float acc[8] = {0.f, 0.f, 0.f, 0.f, 0.f, 0.f, 0.f, 0.f};
  for (int j = b; j < e; j += 4) {
    int i1 = (j + 1 < e) ? j + 1 : j;
    int i2 = (j + 2 < e) ? j + 2 : j;
    int i3 = (j + 3 < e) ? j + 3 : j;
    int s0 = esrc[j], s1 = esrc[i1], s2 = esrc[i2], s3 = esrc[i3];
    bf16x8 r0 = *(const bf16x8*)(xb + (size_t)s0 * DIM + l * 8);
    bf16x8 r1 = *(const bf16x8*)(xb + (size_t)s1 * DIM + l * 8);
    bf16x8 r2 = *(const bf16x8*)(xb + (size_t)s2 * DIM + l * 8);
    bf16x8 r3 = *(const bf16x8*)(xb + (size_t)s3 * DIM + l * 8);
    float m1 = (j + 1 < e) ? 1.f : 0.f;
    float m2 = (j + 2 < e) ? 1.f : 0.f;
    float m3 = (j + 3 < e) ? 1.f : 0.f;
#pragma unroll
    for (int k = 0; k < 8; k++)
      acc[k] += bf2f(r0[k]) + m1 * bf2f(r1[k]) + m2 * bf2f(r2[k]) + m3 * bf2f(r3[k]);
  }
  float inv = 1.0f / fmaxf((float)(e - b), 1.0f);
  bf16x8 ov;
#pragma unroll
  for (int k = 0; k < 8; k++) ov[k] = f2bf(acc[k] * inv);
  *(bf16x8*)(aggb + (size_t)node * DIM + l * 8) = ov;
}

// ================= fused MFMA: both GEMMs, h stays in LDS =================
// 512 threads = 8 thin waves; each wave owns 32 rows x 128 cols.
// Stage-2 stages BOTH output halves in the tile (cols 0..127 = hW,
// cols 128..255 = h@Wr2+bl2 as bf16) and streams them out coalesced:
// hW half -> ab_hw (hWb), partial half -> xb_drefp (dead xb buffer, own rows).
// No f32 dref writes here anymore — gather2 produces dref with a pure write.
__global__ __launch_bounds__(512, 4) void fused_mfma_kernel(
    short* xb_drefp, short* ab_hw,
    const short* __restrict__ Wf1, const float* __restrict__ bl1,
    const short* __restrict__ Wf2, const float* __restrict__ bl2) {
  __shared__ __align__(16) short tile[MBLK][LDK];   // 67.6 KB -> 2 blocks/CU
  const int tid = threadIdx.x;
  const int row0 = blockIdx.x * MBLK;

  // stage A_cat = [aggb | xb] bf16, 16B chunks
  for (int idx = tid; idx < MBLK * 32; idx += 512) {
    int r   = idx >> 5;
    int c16 = idx & 31;
    int row = row0 + r;
    int col = c16 * 8;
    int4 v = make_int4(0, 0, 0, 0);
    if (row < NN) {
      const short* srcp = (col < DIM) ? (ab_hw + (size_t)row * DIM + col)
                                      : (xb_drefp + (size_t)row * DIM + (col - DIM));
      v = *(const int4*)srcp;
    }
    *(int4*)&tile[r][col] = v;
  }
  __syncthreads();

  const int lane = tid & 63;
  const int wv   = tid >> 6;          // 0..7
  const int c    = lane & 15;
  const int quad = lane >> 4;
  const int wrow = (wv & 3) * 32;     // row quarter (32 rows = 2 groups of 16)
  const int ch   = wv >> 2;           // col half

  // ---- stage 1: h = relu(A_cat @ W1 + bl1) -> LDS ----
  {
    bf16x8 af[2][8];
#pragma unroll
    for (int rg = 0; rg < 2; rg++)
#pragma unroll
      for (int kk = 0; kk < 8; kk++)
        af[rg][kk] = *(const bf16x8*)&tile[wrow + rg * 16 + c][kk * 32 + quad * 8];
    __syncthreads();                  // A in regs everywhere -> safe to overwrite tile

#pragma unroll 1
    for (int nn = 0; nn < 8; nn++) {
      int n = ch * 8 + nn;
      const short* wq = Wf1 + ((size_t)(n * 8) << 9) + lane * 8;
      bf16x8 bw[8];
#pragma unroll
      for (int kk = 0; kk < 8; kk++)
        bw[kk] = *(const bf16x8*)(wq + ((size_t)kk << 9));
      f32x4 a0 = {0.f, 0.f, 0.f, 0.f}, a1 = {0.f, 0.f, 0.f, 0.f};
      __builtin_amdgcn_s_setprio(1);
#pragma unroll
      for (int kk = 0; kk < 8; kk++) {
        a0 = __builtin_amdgcn_mfma_f32_16x16x32_bf16(af[0][kk], bw[kk], a0, 0, 0, 0);
        a1 = __builtin_amdgcn_mfma_f32_16x16x32_bf16(af[1][kk], bw[kk], a1, 0, 0, 0);
      }
      __builtin_amdgcn_s_setprio(0);
      float bv = bl1[n * 16 + c];
#pragma unroll
      for (int i = 0; i < 4; i++) {
        tile[wrow +      quad * 4 + i][n * 16 + c] = f2bf(fmaxf(a0[i] + bv, 0.0f));
        tile[wrow + 16 + quad * 4 + i][n * 16 + c] = f2bf(fmaxf(a1[i] + bv, 0.0f));
      }
    }
  }
  __syncthreads();

  // ---- stage 2: [hW | h@Wr2+bl2] -> tile (both halves), then stream out ----
  {
    bf16x8 af[2][8];
#pragma unroll
    for (int rg = 0; rg < 2; rg++)
#pragma unroll
      for (int kk = 0; kk < 8; kk++)
        af[rg][kk] = *(const bf16x8*)&tile[wrow + rg * 16 + c][kk * 32 + quad * 8];
    __syncthreads();                   // all waves done reading h -> safe to overwrite

#pragma unroll 1
    for (int nn = 0; nn < 8; nn++) {
      int n = ch * 8 + nn;
      const short* wq = Wf2 + ((size_t)(n * 8) << 9) + lane * 8;
      bf16x8 bw[8];
#pragma unroll
      for (int kk = 0; kk < 8; kk++)
        bw[kk] = *(const bf16x8*)(wq + ((size_t)kk << 9));
      f32x4 a0 = {0.f, 0.f, 0.f, 0.f}, a1 = {0.f, 0.f, 0.f, 0.f};
      __builtin_amdgcn_s_setprio(1);
#pragma unroll
      for (int kk = 0; kk < 8; kk++) {
        a0 = __builtin_amdgcn_mfma_f32_16x16x32_bf16(af[0][kk], bw[kk], a0, 0, 0, 0);
        a1 = __builtin_amdgcn_mfma_f32_16x16x32_bf16(af[1][kk], bw[kk], a1, 0, 0, 0);
      }
      __builtin_amdgcn_s_setprio(0);
      int col = n * 16 + c;
      float bv = (ch == 1) ? bl2[col - 128] : 0.0f;   // bias only on the Wr2 half
#pragma unroll
      for (int i = 0; i < 4; i++) {
        tile[wrow +      quad * 4 + i][col] = f2bf(a0[i] + bv);
        tile[wrow + 16 + quad * 4 + i][col] = f2bf(a1[i] + bv);
      }
    }
  }
  __syncthreads();

  // stream both halves out coalesced (b128 chunks)
  for (int idx = tid; idx < MBLK * 32; idx += 512) {
    int r   = idx >> 5;
    int c16 = idx & 31;
    int row = row0 + r;
    if (row < NN) {
      int4 v = *(const int4*)&tile[r][c16 * 8];
      if (c16 < 16)
        *(int4*)(ab_hw + (size_t)row * DIM + c16 * 8) = v;
      else
        *(int4*)(xb_drefp + (size_t)row * DIM + (c16 - 16) * 8) = v;
    }
  }
}

// ================= gather2: dref = partial + mean(hWb[src]); bf16 shadow in place ====
// xbuf holds the bf16 partial on entry (own row read), final bf16 on exit.
// dref is a PURE f32 write now (no read-modify-write round trip).
__global__ __launch_bounds__(256) void gather2_kernel(const int* __restrict__ rowptr,
                                                      const int* __restrict__ esrc,
                                                      const short* __restrict__ hWb,
                                                      short* xbuf,
                                                      float* __restrict__ dref) {
  int t = blockIdx.x * 256 + threadIdx.x;
  int node = t >> 4, l = t & 15;
  if (node >= NN) return;
  int b = rowptr[node], e = rowptr[node + 1];
  bf16x8 p = *(const bf16x8*)(xbuf + (size_t)node * DIM + l * 8);  // hoisted partial
  float acc[8] = {0.f, 0.f, 0.f, 0.f, 0.f, 0.f, 0.f, 0.f};
  for (int j = b; j < e; j += 4) {
    int i1 = (j + 1 < e) ? j + 1 : j;
    int i2 = (j + 2 < e) ? j + 2 : j;
    int i3 = (j + 3 < e) ? j + 3 : j;
    int s0 = esrc[j], s1 = esrc[i1], s2 = esrc[i2], s3 = esrc[i3];
    bf16x8 r0 = *(const bf16x8*)(hWb + (size_t)s0 * DIM + l * 8);
    bf16x8 r1 = *(const bf16x8*)(hWb + (size_t)s1 * DIM + l * 8);
    bf16x8 r2 = *(const bf16x8*)(hWb + (size_t)s2 * DIM + l * 8);
    bf16x8 r3 = *(const bf16x8*)(hWb + (size_t)s3 * DIM + l * 8);
    float m1 = (j + 1 < e) ? 1.f : 0.f;
    float m2 = (j + 2 < e) ? 1.f : 0.f;
    float m3 = (j + 3 < e) ? 1.f : 0.f;
#pragma unroll
    for (int k = 0; k < 8; k++)
      acc[k] += bf2f(r0[k]) + m1 * bf2f(r1[k]) + m2 * bf2f(r2[k]) + m3 * bf2f(r3[k]);
  }
  float inv = 1.0f / fmaxf((float)(e - b), 1.0f);
  float fin[8];
  bf16x8 ov;
#pragma unroll
  for (int k = 0; k < 8; k++) {
    fin[k] = bf2f(p[k]) + acc[k] * inv;
    ov[k] = f2bf(fin[k]);
  }
  float* dr = dref + (size_t)node * DIM + l * 8;
  *(float4*)(dr)     = make_float4(fin[0], fin[1], fin[2], fin[3]);
  *(float4*)(dr + 4) = make_float4(fin[4], fin[5], fin[6], fin[7]);
  *(bf16x8*)(xbuf + (size_t)node * DIM + l * 8) = ov;
}

// ================= edge scoring from bf16 shadow (edge-parallel) =================
__global__ __launch_bounds__(256) void score_kernel(const int* __restrict__ src,
                                                    const int* __restrict__ dst,
                                                    const short* __restrict__ drefb,
                                                    float* __restrict__ out) {
  int t = blockIdx.x * 256 + threadIdx.x;
  int e = t >> 4, l = t & 15;
  if (e >= NE) return;
  int s = src[e], d = dst[e];
  bf16x8 a = *(const bf16x8*)(drefb + (size_t)s * DIM + l * 8);
  bf16x8 b = *(const bf16x8*)(drefb + (size_t)d * DIM + l * 8);
  float sum = 0.f;
#pragma unroll
  for (int k = 0; k < 8; k++) sum += bf2f(a[k]) * bf2f(b[k]);
#pragma unroll
  for (int off = 1; off < 16; off <<= 1) sum += __shfl_xor(sum, off, 16);
  if (l == 0) out[e] = sum;
}

extern "C" void kernel_launch(void* const* d_in, const int* in_sizes, int n_in,
                              void* d_out, int out_size, void* d_ws, size_t ws_size,
                              hipStream_t stream) {
  const int* ei    = (const int*)d_in[0];
  const int* src   = ei;
  const int* dst   = ei + NE;
  // d_in[1] = edge_attr (unused by the reference)
  const float* movie = (const float*)d_in[2];
  const float* user  = (const float*)d_in[3];
  const float* Wl1   = (const float*)d_in[4];
  const float* bl1   = (const float*)d_in[5];
  const float* Wr1   = (const float*)d_in[6];
  const float* Wl2   = (const float*)d_in[7];
  const float* bl2   = (const float*)d_in[8];
  const float* Wr2   = (const float*)d_in[9];

  float* out  = (float*)d_out;       // [NE] ratings
  float* dref = out + NE;            // [NN*DIM] refined (f32 output)

  // workspace (~81.6 MB): ints | xb(+drefp/drefb alias) | aggb(+hWb alias) | Wf1 | Wf2
  int* degi   = (int*)d_ws;                    // [NN] (zeroed)
  int* cnt    = degi + NN;                     // [NN] (zeroed)
  int* pre    = cnt + NN;                      // [NN]
  int* bsum   = pre + NN;                      // [1024]
  int* rowptr = bsum + 1024;                   // [NN+1]
  int* esrc   = rowptr + NN + 1;               // [NE] src node per CSR slot
  short* xb   = (short*)(((uintptr_t)(esrc + NE) + 15) & ~(uintptr_t)15);  // [NN*DIM] bf16
  short* aggb = xb + (size_t)NN * DIM;         // [NN*DIM] bf16 (later reused as hWb)
  short* Wf1  = aggb + (size_t)NN * DIM;       // [65536]
  short* Wf2  = Wf1 + 65536;                   // [65536]
  short* hWb   = aggb;                         // alias: fused overwrites its own rows
  // xb aliases: partial (h@Wr2+bl2, written by fused) then final bf16 shadow (gather2)

  hipMemsetAsync(degi, 0, (size_t)2 * NN * sizeof(int), stream);

  deg_kernel<<<(NE + 255) / 256, 256, 0, stream>>>(dst, degi);
  scan1_kernel<<<NB_SCAN, 256, 0, stream>>>(degi, pre, bsum);
  scan2_kernel<<<1, 1024, 0, stream>>>(bsum);
  scan3_kernel<<<NB_SCAN, 256, 0, stream>>>(pre, bsum, rowptr);
  csr_scatter_kernel<<<(NE + 255) / 256, 256, 0, stream>>>(src, dst, rowptr, cnt, esrc);
  convx_kernel<<<NN * DIM / 8 / 256, 256, 0, stream>>>(movie, user, xb);
  convw_kernel<<<16384 / 256, 256, 0, stream>>>(Wl1, Wr1, Wl2, Wr2, Wf1, Wf2);
  gather1_kernel<<<NN * 16 / 256, 256, 0, stream>>>(rowptr, esrc, xb, aggb);
  fused_mfma_kernel<<<(NN + MBLK - 1) / MBLK, 512, 0, stream>>>(
      xb, aggb, Wf1, bl1, Wf2, bl2);
  gather2_kernel<<<NN * 16 / 256, 256, 0, stream>>>(rowptr, esrc, hWb, xb, dref);
  score_kernel<<<NE * 16 / 256, 256, 0, stream>>>(src, dst, xb, out);
}